// Round 5
// baseline (476.580 us; speedup 1.0000x reference)
//
#include <hip/hip_runtime.h>
#include <stdint.h>

// Problem constants (B,S,D fixed by the reference)
#define B_  4
#define S_  2048
#define D_  1024
#define DK_ 1024
#define DV_ 1024

typedef __attribute__((ext_vector_type(8)))  short short8;    // 8 bf16 = 4 VGPRs (MFMA A/B frag)
typedef __attribute__((ext_vector_type(16))) float floatx16;  // 32x32 MFMA C/D frag

// async global->LDS DMA, 16B per lane, wave-uniform LDS base (lane scatters +lane*16B)
#define ASYNC16(gsrc, ldst)                                                        \
  __builtin_amdgcn_global_load_lds(                                                \
      (const __attribute__((address_space(1))) unsigned int*)(gsrc),               \
      (__attribute__((address_space(3))) unsigned int*)(ldst), 16, 0, 0)

// round-to-nearest-even fp32 -> bf16
__device__ __forceinline__ unsigned short f2bf(float f) {
  union { float f; uint32_t u; } v; v.f = f;
  uint32_t r = v.u + 0x7fffu + ((v.u >> 16) & 1u);
  return (unsigned short)(r >> 16);
}
__device__ __forceinline__ float bf2f(unsigned short h) {
  union { float f; uint32_t u; } v; v.u = ((uint32_t)h) << 16;
  return v.f;
}

// ---------------- fp32 -> bf16, 3 tensors in one dispatch (z selects) ----------------
__global__ __launch_bounds__(256) void cvt3_f32_bf16(const float* __restrict__ a,
                                                     const float* __restrict__ b,
                                                     const float* __restrict__ c,
                                                     unsigned short* __restrict__ out, int n4) {
  const float* in = (blockIdx.z == 0) ? a : (blockIdx.z == 1) ? b : c;
  unsigned short* o = out + (long)blockIdx.z * n4 * 4;
  int i = blockIdx.x * 256 + threadIdx.x;
  if (i >= n4) return;
  float4 v = ((const float4*)in)[i];
  ushort4 u;
  u.x = f2bf(v.x); u.y = f2bf(v.y); u.z = f2bf(v.z); u.w = f2bf(v.w);
  ((ushort4*)o)[i] = u;
}

// ---------------- transpose fp32 [rows,cols] -> bf16 [cols,rows], 3 weights (z) ----------------
__global__ __launch_bounds__(256) void transpose3_f32_bf16(const float* __restrict__ W0,
                                                           const float* __restrict__ W1,
                                                           const float* __restrict__ W2,
                                                           unsigned short* __restrict__ out,
                                                           int rows, int cols) {
  const float* in = (blockIdx.z == 0) ? W0 : (blockIdx.z == 1) ? W1 : W2;
  unsigned short* o = out + (long)blockIdx.z * rows * cols;
  __shared__ float tile[32][33];
  int bx = blockIdx.x * 32, by = blockIdx.y * 32;
  int tx = threadIdx.x & 31, ty = threadIdx.x >> 5;
  for (int r = ty; r < 32; r += 8)
    tile[r][tx] = in[(long)(by + r) * cols + bx + tx];
  __syncthreads();
  for (int r = ty; r < 32; r += 8)
    o[(long)(bx + r) * rows + by + tx] = f2bf(tile[tx][r]);
}

// ---------------- transpose bf16 [rows,cols] -> bf16 [cols,rows], batched on z ----------------
__global__ __launch_bounds__(256) void transpose_bf16_batched(const unsigned short* __restrict__ in,
                                                              unsigned short* __restrict__ out,
                                                              int rows, int cols) {
  in  += (long)blockIdx.z * rows * cols;
  out += (long)blockIdx.z * rows * cols;
  __shared__ unsigned short tile[32][33];
  int bx = blockIdx.x * 32, by = blockIdx.y * 32;
  int tx = threadIdx.x & 31, ty = threadIdx.x >> 5;
  for (int r = ty; r < 32; r += 8)
    tile[r][tx] = in[(long)(by + r) * cols + bx + tx];
  __syncthreads();
  for (int r = ty; r < 32; r += 8)
    out[(long)(bx + r) * rows + by + tx] = tile[tx][r];
}

__device__ __forceinline__ void storeC(float* p, float v)          { *p = v; }
__device__ __forceinline__ void storeC(unsigned short* p, float v) { *p = f2bf(v); }

// ---------------- bf16 BT GEMM, 32x32x16 MFMA, BK=64, K-MAJOR LDS ----------------
// C[M,N] = scale * (A[M,K] . B[N,K]^T) + bias.  128x128 block tile, 4 waves (2x2 of 64x64).
// LDS layout (NEW): As[half][kchunk][row] with one 16B slot per (kchunk,row) —
// frag reads are lane->consecutive-16B-slots (8x128B segments, the LDS minimum).
// Round-3/4 evidence: row-major [128][32] tile cost 12 extra cyc per ds_read_b128
// (32 rows = 16 segments); column swizzles can't fix that (identical 18.87M counter).
// DMA: wave w stages k-half (w&1) of A (waves 0,1) or B (waves 2,3): 8 ASYNC16,
// lane = global row, slot = kc*128 + row -> wave-uniform base + lane*16B (m104/m108 ok).
// A/B frag (32x32x16): m(or n)=lane&31, kchunk=(s&1)*2+(lane>>5).
// C/D (m74/m101 verified): col=lane&31, row=(reg&3)+8*(reg>>2)+4*(lane>>5).
// NOUT=3: fused QKV — blockIdx.x selects (A,C,bias) triple, B rows span 3072 (WqT||WkT||WvT).
template <typename OutT, int NOUT>
__global__ __launch_bounds__(256)
void gemm_bt32(const unsigned short* __restrict__ A0, const unsigned short* __restrict__ A1,
               const unsigned short* __restrict__ A2, const unsigned short* __restrict__ Bm,
               OutT* __restrict__ C0, OutT* __restrict__ C1, OutT* __restrict__ C2,
               const float* __restrict__ b0, const float* __restrict__ b1,
               const float* __restrict__ b2,
               int N, int K, long sA, long sB, long sC, float scale) {
  __shared__ __align__(16) unsigned short As[2][4][1024];  // [half][kchunk][row*8] 16KB
  __shared__ __align__(16) unsigned short Bs[2][4][1024];
  const int tid  = threadIdx.x;
  const int lane = tid & 63, wave = tid >> 6;
  const int wm = (wave >> 1) * 64, wn = (wave & 1) * 64;
  const int lm = lane & 31;           // row/col within 32-wide MFMA tile
  const int hi = lane >> 5;           // k-subgroup within a k16 step
  const long zb = blockIdx.z;
  const int m0  = blockIdx.y * 128;
  const int n0g = blockIdx.x * 128;

  // output/bias/A select (wave-uniform)
  const unsigned short* A = A0;
  OutT* C = C0;
  const float* bias = b0;
  int n0 = n0g;
  if (NOUT == 3) {
    int sel = n0g >> 10;
    n0 = n0g & 1023;
    if (sel == 1)      { A = A1; C = C1; bias = b1; }
    else if (sel == 2) { A = A2; C = C2; bias = b2; }
  }
  A += zb * sA;
  const unsigned short* Bp = Bm + zb * sB;
  C += zb * sC;

  // ---- staging: wave w stages k-half (w&1) of A (w<2) or B (w>=2); lane = row ----
  const int hA = wave & 1;
  const unsigned short* gsrc = (wave < 2)
      ? (A  + (long)(m0  + lane) * K + hA * 32)
      : (Bp + (long)(n0g + lane) * K + hA * 32);
  unsigned short (*ldst)[1024] = (wave < 2) ? As[hA] : Bs[hA];
  const long rowStep = 64 * (long)K;   // rows 64..127 of the tile

  floatx16 acc[2][2] = {};

  for (int kt = 0; kt < K; kt += 64) {
    __syncthreads();                    // previous compute done reading LDS
    const unsigned short* g = gsrc + kt;
#pragma unroll
    for (int kc = 0; kc < 4; kc++) {
      ASYNC16(g + kc * 8,           &ldst[kc][0]);
      ASYNC16(g + kc * 8 + rowStep, &ldst[kc][512]);
    }
    __syncthreads();                    // drains vmcnt -> tiles visible

#pragma unroll
    for (int s = 0; s < 4; s++) {       // 4 k16 steps; h = s>>1 half
      const int h  = s >> 1;
      const int kc = (s & 1) * 2 + hi;  // k-chunk for this lane's frag
      short8 af[2], bf[2];
#pragma unroll
      for (int i = 0; i < 2; i++)
        af[i] = *(const short8*)&As[h][kc][(wm + i * 32 + lm) * 8];
#pragma unroll
      for (int j = 0; j < 2; j++)
        bf[j] = *(const short8*)&Bs[h][kc][(wn + j * 32 + lm) * 8];
#pragma unroll
      for (int i = 0; i < 2; i++)
#pragma unroll
        for (int j = 0; j < 2; j++)
          acc[i][j] = __builtin_amdgcn_mfma_f32_32x32x16_bf16(af[i], bf[j], acc[i][j], 0, 0, 0);
    }
  }

  // ---- epilogue: C/D col=lane&31, row=(r&3)+8*(r>>2)+4*hi ----
#pragma unroll
  for (int i = 0; i < 2; i++) {
#pragma unroll
    for (int j = 0; j < 2; j++) {
      const int col = n0 + wn + j * 32 + lm;
      const float bv = bias ? bias[col] : 0.f;
#pragma unroll
      for (int r = 0; r < 16; r++) {
        const int row = m0 + wm + i * 32 + (r & 3) + ((r >> 2) << 3) + (hi << 2);
        storeC(C + (long)row * N + col, acc[i][j][r] * scale + bv);
      }
    }
  }
}

// ---------------- row softmax: bf16 [rows,2048] -> bf16 probs, vectorized ----------------
__global__ __launch_bounds__(256) void softmax_rows_bf16(const unsigned short* __restrict__ Sc,
                                                         unsigned short* __restrict__ P) {
  const long row = blockIdx.x;
  const int tid = threadIdx.x;
  short8 xv = ((const short8*)(Sc + row * 2048))[tid];
  float v[8];
  float m = -3.4e38f;
#pragma unroll
  for (int j = 0; j < 8; j++) { v[j] = bf2f((unsigned short)xv[j]); m = fmaxf(m, v[j]); }
#pragma unroll
  for (int off = 32; off > 0; off >>= 1) m = fmaxf(m, __shfl_xor(m, off, 64));
  __shared__ float redm[4], reds[4];
  if ((tid & 63) == 0) redm[tid >> 6] = m;
  __syncthreads();
  m = fmaxf(fmaxf(redm[0], redm[1]), fmaxf(redm[2], redm[3]));
  float s = 0.f;
#pragma unroll
  for (int j = 0; j < 8; j++) { v[j] = __expf(v[j] - m); s += v[j]; }
#pragma unroll
  for (int off = 32; off > 0; off >>= 1) s += __shfl_xor(s, off, 64);
  if ((tid & 63) == 0) reds[tid >> 6] = s;
  __syncthreads();
  s = reds[0] + reds[1] + reds[2] + reds[3];
  float inv = 1.f / s;
  short8 ov;
#pragma unroll
  for (int j = 0; j < 8; j++) ov[j] = (short)f2bf(v[j] * inv);
  ((short8*)(P + row * 2048))[tid] = ov;
}

extern "C" void kernel_launch(void* const* d_in, const int* in_sizes, int n_in,
                              void* d_out, int out_size, void* d_ws, size_t ws_size,
                              hipStream_t stream) {
  const float* q_in = (const float*)d_in[0];
  const float* k_in = (const float*)d_in[1];
  const float* v_in = (const float*)d_in[2];
  const float* Wq   = (const float*)d_in[3];
  const float* bq   = (const float*)d_in[4];
  const float* Wk   = (const float*)d_in[5];
  const float* bk   = (const float*)d_in[6];
  const float* Wv   = (const float*)d_in[7];
  const float* bv   = (const float*)d_in[8];
  float* out = (float*)d_out;

  // ---- workspace layout; scoresB (bf16, 33.5MB) overlays dead qb/kb regions ----
  char* ws = (char*)d_ws;
  const long nX = (long)B_ * S_ * D_;   // 8388608 elems
  const long nW = (long)D_ * DK_;       // 1048576
  unsigned short* qb  = (unsigned short*)(ws);
  unsigned short* kb  = qb + nX;
  unsigned short* vb  = kb + nX;
  unsigned short* WqT = vb + nX;        // WqT||WkT||WvT contiguous = B[3072,1024]
  unsigned short* Vb  = WqT + 3 * nW;   // dead after V-transpose
  unsigned short* Qb  = Vb + nX;
  unsigned short* Kb  = Qb + nX;
  unsigned short* Vt  = Kb + nX;        // [B, DV, S]
  unsigned short* scoresB = (unsigned short*)ws;  // bf16 [B,S,S] overlay: qb/kb/vb dead by then
  unsigned short* attn    = Vt + nX;

  dim3 blk(256);

  // 1) inputs -> bf16 (one dispatch, z selects tensor; qb/kb/vb contiguous)
  {
    int n4 = (int)(nX / 4);
    dim3 g(n4 / 256, 1, 3);
    cvt3_f32_bf16<<<g, blk, 0, stream>>>(q_in, k_in, v_in, qb, n4);
  }
  // 2) W^T (bf16), one dispatch
  {
    dim3 g(DK_ / 32, D_ / 32, 3);
    transpose3_f32_bf16<<<g, blk, 0, stream>>>(Wq, Wk, Wv, WqT, D_, DK_);
  }
  // 3) fused QKV projection: x-tiles [0,8)->Q, [8,16)->K, [16,24)->V
  {
    dim3 g(3 * DK_ / 128, (B_ * S_) / 128, 1);
    gemm_bt32<unsigned short, 3><<<g, blk, 0, stream>>>(
        qb, kb, vb, WqT, Qb, Kb, Vb, bq, bk, bv, DK_, D_, 0, 0, 0, 1.f);
  }
  // 4) V -> V^T per batch
  {
    dim3 g(DV_ / 32, S_ / 32, B_);
    transpose_bf16_batched<<<g, blk, 0, stream>>>(Vb, Vt, S_, DV_);
  }
  // 5) scores = Q K^T / 32 -> bf16, batched
  {
    dim3 g(S_ / 128, S_ / 128, B_);
    gemm_bt32<unsigned short, 1><<<g, blk, 0, stream>>>(
        Qb, nullptr, nullptr, Kb, scoresB, nullptr, nullptr, nullptr, nullptr, nullptr,
        S_, DK_, (long)S_ * DK_, (long)S_ * DK_, (long)S_ * S_, 0.03125f);
  }
  // 6) softmax rows -> bf16 attn
  {
    dim3 g(B_ * S_);
    softmax_rows_bf16<<<g, blk, 0, stream>>>(scoresB, attn);
  }
  // 7) out = attn @ V = attn[2048,2048] x Vt[1024,2048]^T, fp32 out
  {
    dim3 g(DV_ / 128, S_ / 128, B_);
    gemm_bt32<float, 1><<<g, blk, 0, stream>>>(
        attn, nullptr, nullptr, Vt, out, nullptr, nullptr, nullptr, nullptr, nullptr,
        DV_, S_, (long)S_ * S_, (long)DV_ * S_, (long)S_ * DV_, 1.f);
  }
}

// Round 6
// 354.523 us; speedup vs baseline: 1.3443x; 1.3443x over previous
//
#include <hip/hip_runtime.h>
#include <stdint.h>

// Problem constants (B,S,D fixed by the reference)
#define B_  4
#define S_  2048
#define D_  1024
#define DK_ 1024
#define DV_ 1024

typedef __attribute__((ext_vector_type(8)))  short short8;    // 8 bf16 = 4 VGPRs (MFMA A/B frag)
typedef __attribute__((ext_vector_type(16))) float floatx16;  // 32x32 MFMA C/D frag

// async global->LDS DMA, 16B per lane, wave-uniform LDS base (lane scatters +lane*16B)
#define ASYNC16(gsrc, ldst)                                                        \
  __builtin_amdgcn_global_load_lds(                                                \
      (const __attribute__((address_space(1))) unsigned int*)(gsrc),               \
      (__attribute__((address_space(3))) unsigned int*)(ldst), 16, 0, 0)

// round-to-nearest-even fp32 -> bf16
__device__ __forceinline__ unsigned short f2bf(float f) {
  union { float f; uint32_t u; } v; v.f = f;
  uint32_t r = v.u + 0x7fffu + ((v.u >> 16) & 1u);
  return (unsigned short)(r >> 16);
}
__device__ __forceinline__ float bf2f(unsigned short h) {
  union { float f; uint32_t u; } v; v.u = ((uint32_t)h) << 16;
  return v.f;
}

// ---------------- fp32 -> bf16, 3 tensors in one dispatch (z selects) ----------------
__global__ __launch_bounds__(256) void cvt3_f32_bf16(const float* __restrict__ a,
                                                     const float* __restrict__ b,
                                                     const float* __restrict__ c,
                                                     unsigned short* __restrict__ out, int n4) {
  const float* in = (blockIdx.z == 0) ? a : (blockIdx.z == 1) ? b : c;
  unsigned short* o = out + (long)blockIdx.z * n4 * 4;
  int i = blockIdx.x * 256 + threadIdx.x;
  if (i >= n4) return;
  float4 v = ((const float4*)in)[i];
  ushort4 u;
  u.x = f2bf(v.x); u.y = f2bf(v.y); u.z = f2bf(v.z); u.w = f2bf(v.w);
  ((ushort4*)o)[i] = u;
}

// ---------------- transpose fp32 [rows,cols] -> bf16 [cols,rows], 3 weights (z) ----------------
__global__ __launch_bounds__(256) void transpose3_f32_bf16(const float* __restrict__ W0,
                                                           const float* __restrict__ W1,
                                                           const float* __restrict__ W2,
                                                           unsigned short* __restrict__ out,
                                                           int rows, int cols) {
  const float* in = (blockIdx.z == 0) ? W0 : (blockIdx.z == 1) ? W1 : W2;
  unsigned short* o = out + (long)blockIdx.z * rows * cols;
  __shared__ float tile[32][33];
  int bx = blockIdx.x * 32, by = blockIdx.y * 32;
  int tx = threadIdx.x & 31, ty = threadIdx.x >> 5;
  for (int r = ty; r < 32; r += 8)
    tile[r][tx] = in[(long)(by + r) * cols + bx + tx];
  __syncthreads();
  for (int r = ty; r < 32; r += 8)
    o[(long)(bx + r) * rows + by + tx] = f2bf(tile[tx][r]);
}

// ---------------- transpose bf16 [rows,cols] -> bf16 [cols,rows], batched on z ----------------
__global__ __launch_bounds__(256) void transpose_bf16_batched(const unsigned short* __restrict__ in,
                                                              unsigned short* __restrict__ out,
                                                              int rows, int cols) {
  in  += (long)blockIdx.z * rows * cols;
  out += (long)blockIdx.z * rows * cols;
  __shared__ unsigned short tile[32][33];
  int bx = blockIdx.x * 32, by = blockIdx.y * 32;
  int tx = threadIdx.x & 31, ty = threadIdx.x >> 5;
  for (int r = ty; r < 32; r += 8)
    tile[r][tx] = in[(long)(by + r) * cols + bx + tx];
  __syncthreads();
  for (int r = ty; r < 32; r += 8)
    out[(long)(bx + r) * rows + by + tx] = tile[tx][r];
}

__device__ __forceinline__ void storeC(float* p, float v)          { *p = v; }
__device__ __forceinline__ void storeC(unsigned short* p, float v) { *p = f2bf(v); }

// ---------------- bf16 BT GEMM, 32x32x16 MFMA, BK=64, XOR(row>>1) SWIZZLE ----------------
// C[M,N] = scale * (A[M,K] . B[N,K]^T) + bias.  128x128 block tile, 4 waves (2x2 of 64x64).
// Row-major LDS [h][128][32] (coalesced DMA, round-4 structure). Bank math for frag
// b128 reads: bank = 16*(row&1) + 4*kc + j.  Round-3's kc^=(row&3) failed: row&3's low
// bit == parity bit -> only 2 kc values per parity group (8-way). Correct swizzle is
// kc_lds = kc ^ ((row>>1)&3): 4 lanes per bank-quad -> 8 accesses/bank, the b128 floor.
// DMA source applies the same XOR within each 64B line -> coalescing preserved:
// lane l of chunk c: row = 16c+(l>>2), global kc = (l&3) ^ ((l>>3)&3)  [ (row>>1)&3 = (l>>3)&3 ].
// Frag read: row=wm+i*32+lm -> (row>>1)&3 = (lm>>1)&3.
// A/B frag (32x32x16): m(or n)=lane&31, k-chunk=(s&1)*2+(lane>>5).
// C/D (m74/m101 verified): col=lane&31, row=(reg&3)+8*(reg>>2)+4*(lane>>5).
// NOUT=3: fused QKV — blockIdx.x selects (A,C,bias) triple, B rows span 3072 (WqT||WkT||WvT).
template <typename OutT, int NOUT>
__global__ __launch_bounds__(256)
void gemm_bt32(const unsigned short* __restrict__ A0, const unsigned short* __restrict__ A1,
               const unsigned short* __restrict__ A2, const unsigned short* __restrict__ Bm,
               OutT* __restrict__ C0, OutT* __restrict__ C1, OutT* __restrict__ C2,
               const float* __restrict__ b0, const float* __restrict__ b1,
               const float* __restrict__ b2,
               int N, int K, long sA, long sB, long sC, float scale) {
  __shared__ __align__(16) unsigned short As[2][128 * 32];
  __shared__ __align__(16) unsigned short Bs[2][128 * 32];
  const int tid  = threadIdx.x;
  const int lane = tid & 63, wave = tid >> 6;
  const int wm = (wave >> 1) * 64, wn = (wave & 1) * 64;
  const int lm = lane & 31;           // row/col within 32-wide MFMA tile
  const int hi = lane >> 5;           // k-subgroup within a k16 step
  const long zb = blockIdx.z;
  const int m0  = blockIdx.y * 128;
  const int n0g = blockIdx.x * 128;

  // output/bias/A select (wave-uniform)
  const unsigned short* A = A0;
  OutT* C = C0;
  const float* bias = b0;
  int n0 = n0g;
  if (NOUT == 3) {
    int sel = n0g >> 10;
    n0 = n0g & 1023;
    if (sel == 1)      { A = A1; C = C1; bias = b1; }
    else if (sel == 2) { A = A2; C = C2; bias = b2; }
  }
  A += zb * sA;
  const unsigned short* Bp = Bm + zb * sB;
  C += zb * sC;

  // ---- staging: per wave 4 A-chunks + 4 B-chunks per K=64 iter (coalesced, swizzled src) ----
  const int rr = lane >> 2;                              // 0..15 row within chunk
  const int cc = (((lane & 3) ^ ((lane >> 3) & 3)) * 8); // swizzled col chunk, same 64B line
  const unsigned short* agA = A  + (long)(m0  + 16 * wave + rr) * K + cc;
  const unsigned short* agB = Bp + (long)(n0g + 16 * wave + rr) * K + cc;
  const unsigned short* ag0 = agA;                 // h=0, rows 16w..
  const unsigned short* ag1 = agA + 32;            // h=1, rows 16w..
  const unsigned short* ag2 = agA + 64 * (long)K;  // h=0, rows 64+16w..
  const unsigned short* ag3 = agA + 64 * (long)K + 32;
  const unsigned short* bg0 = agB;
  const unsigned short* bg1 = agB + 32;
  const unsigned short* bg2 = agB + 64 * (long)K;
  const unsigned short* bg3 = agB + 64 * (long)K + 32;
  unsigned short* al0 = &As[0][wave * 512];
  unsigned short* al1 = &As[1][wave * 512];
  unsigned short* al2 = &As[0][(wave + 4) * 512];
  unsigned short* al3 = &As[1][(wave + 4) * 512];
  unsigned short* bl0 = &Bs[0][wave * 512];
  unsigned short* bl1 = &Bs[1][wave * 512];
  unsigned short* bl2 = &Bs[0][(wave + 4) * 512];
  unsigned short* bl3 = &Bs[1][(wave + 4) * 512];

  floatx16 acc[2][2] = {};
  const int sw = (lm >> 1) & 3;       // frag-read swizzle term ((row>>1)&3)

  for (int kt = 0; kt < K; kt += 64) {
    __syncthreads();                    // previous compute done reading LDS
    ASYNC16(ag0, al0); ASYNC16(ag1, al1); ASYNC16(ag2, al2); ASYNC16(ag3, al3);
    ASYNC16(bg0, bl0); ASYNC16(bg1, bl1); ASYNC16(bg2, bl2); ASYNC16(bg3, bl3);
    __syncthreads();                    // drains vmcnt -> tiles visible

#pragma unroll
    for (int s = 0; s < 4; s++) {       // 4 k16 steps; h = s>>1 half
      const int h   = s >> 1;
      const int off = (((s & 1) * 2 + hi) ^ sw) * 8;   // swizzled element offset in 32-col row
      short8 af[2], bf[2];
#pragma unroll
      for (int i = 0; i < 2; i++)
        af[i] = *(const short8*)&As[h][(wm + i * 32 + lm) * 32 + off];
#pragma unroll
      for (int j = 0; j < 2; j++)
        bf[j] = *(const short8*)&Bs[h][(wn + j * 32 + lm) * 32 + off];
#pragma unroll
      for (int i = 0; i < 2; i++)
#pragma unroll
        for (int j = 0; j < 2; j++)
          acc[i][j] = __builtin_amdgcn_mfma_f32_32x32x16_bf16(af[i], bf[j], acc[i][j], 0, 0, 0);
    }
    ag0 += 64; ag1 += 64; ag2 += 64; ag3 += 64;
    bg0 += 64; bg1 += 64; bg2 += 64; bg3 += 64;
  }

  // ---- epilogue: C/D col=lane&31, row=(r&3)+8*(r>>2)+4*hi ----
#pragma unroll
  for (int i = 0; i < 2; i++) {
#pragma unroll
    for (int j = 0; j < 2; j++) {
      const int col = n0 + wn + j * 32 + lm;
      const float bv = bias ? bias[col] : 0.f;
#pragma unroll
      for (int r = 0; r < 16; r++) {
        const int row = m0 + wm + i * 32 + (r & 3) + ((r >> 2) << 3) + (hi << 2);
        storeC(C + (long)row * N + col, acc[i][j][r] * scale + bv);
      }
    }
  }
}

// ---------------- row softmax: bf16 [rows,2048] -> bf16 probs, vectorized ----------------
__global__ __launch_bounds__(256) void softmax_rows_bf16(const unsigned short* __restrict__ Sc,
                                                         unsigned short* __restrict__ P) {
  const long row = blockIdx.x;
  const int tid = threadIdx.x;
  short8 xv = ((const short8*)(Sc + row * 2048))[tid];
  float v[8];
  float m = -3.4e38f;
#pragma unroll
  for (int j = 0; j < 8; j++) { v[j] = bf2f((unsigned short)xv[j]); m = fmaxf(m, v[j]); }
#pragma unroll
  for (int off = 32; off > 0; off >>= 1) m = fmaxf(m, __shfl_xor(m, off, 64));
  __shared__ float redm[4], reds[4];
  if ((tid & 63) == 0) redm[tid >> 6] = m;
  __syncthreads();
  m = fmaxf(fmaxf(redm[0], redm[1]), fmaxf(redm[2], redm[3]));
  float s = 0.f;
#pragma unroll
  for (int j = 0; j < 8; j++) { v[j] = __expf(v[j] - m); s += v[j]; }
#pragma unroll
  for (int off = 32; off > 0; off >>= 1) s += __shfl_xor(s, off, 64);
  if ((tid & 63) == 0) reds[tid >> 6] = s;
  __syncthreads();
  s = reds[0] + reds[1] + reds[2] + reds[3];
  float inv = 1.f / s;
  short8 ov;
#pragma unroll
  for (int j = 0; j < 8; j++) ov[j] = (short)f2bf(v[j] * inv);
  ((short8*)(P + row * 2048))[tid] = ov;
}

extern "C" void kernel_launch(void* const* d_in, const int* in_sizes, int n_in,
                              void* d_out, int out_size, void* d_ws, size_t ws_size,
                              hipStream_t stream) {
  const float* q_in = (const float*)d_in[0];
  const float* k_in = (const float*)d_in[1];
  const float* v_in = (const float*)d_in[2];
  const float* Wq   = (const float*)d_in[3];
  const float* bq   = (const float*)d_in[4];
  const float* Wk   = (const float*)d_in[5];
  const float* bk   = (const float*)d_in[6];
  const float* Wv   = (const float*)d_in[7];
  const float* bv   = (const float*)d_in[8];
  float* out = (float*)d_out;

  // ---- workspace layout; scoresB (bf16, 33.5MB) overlays dead qb/kb regions ----
  char* ws = (char*)d_ws;
  const long nX = (long)B_ * S_ * D_;   // 8388608 elems
  const long nW = (long)D_ * DK_;       // 1048576
  unsigned short* qb  = (unsigned short*)(ws);
  unsigned short* kb  = qb + nX;
  unsigned short* vb  = kb + nX;
  unsigned short* WqT = vb + nX;        // WqT||WkT||WvT contiguous = B[3072,1024]
  unsigned short* Vb  = WqT + 3 * nW;   // dead after V-transpose
  unsigned short* Qb  = Vb + nX;
  unsigned short* Kb  = Qb + nX;
  unsigned short* Vt  = Kb + nX;        // [B, DV, S]
  unsigned short* scoresB = (unsigned short*)ws;  // bf16 [B,S,S] overlay: qb/kb/vb dead by then
  unsigned short* attn    = Vt + nX;

  dim3 blk(256);

  // 1) inputs -> bf16 (one dispatch, z selects tensor; qb/kb/vb contiguous)
  {
    int n4 = (int)(nX / 4);
    dim3 g(n4 / 256, 1, 3);
    cvt3_f32_bf16<<<g, blk, 0, stream>>>(q_in, k_in, v_in, qb, n4);
  }
  // 2) W^T (bf16), one dispatch
  {
    dim3 g(DK_ / 32, D_ / 32, 3);
    transpose3_f32_bf16<<<g, blk, 0, stream>>>(Wq, Wk, Wv, WqT, D_, DK_);
  }
  // 3) fused QKV projection: x-tiles [0,8)->Q, [8,16)->K, [16,24)->V
  {
    dim3 g(3 * DK_ / 128, (B_ * S_) / 128, 1);
    gemm_bt32<unsigned short, 3><<<g, blk, 0, stream>>>(
        qb, kb, vb, WqT, Qb, Kb, Vb, bq, bk, bv, DK_, D_, 0, 0, 0, 1.f);
  }
  // 4) V -> V^T per batch
  {
    dim3 g(DV_ / 32, S_ / 32, B_);
    transpose_bf16_batched<<<g, blk, 0, stream>>>(Vb, Vt, S_, DV_);
  }
  // 5) scores = Q K^T / 32 -> bf16, batched
  {
    dim3 g(S_ / 128, S_ / 128, B_);
    gemm_bt32<unsigned short, 1><<<g, blk, 0, stream>>>(
        Qb, nullptr, nullptr, Kb, scoresB, nullptr, nullptr, nullptr, nullptr, nullptr,
        S_, DK_, (long)S_ * DK_, (long)S_ * DK_, (long)S_ * S_, 0.03125f);
  }
  // 6) softmax rows -> bf16 attn
  {
    dim3 g(B_ * S_);
    softmax_rows_bf16<<<g, blk, 0, stream>>>(scoresB, attn);
  }
  // 7) out = attn @ V = attn[2048,2048] x Vt[1024,2048]^T, fp32 out
  {
    dim3 g(DV_ / 128, S_ / 128, B_);
    gemm_bt32<float, 1><<<g, blk, 0, stream>>>(
        attn, nullptr, nullptr, Vt, out, nullptr, nullptr, nullptr, nullptr, nullptr,
        DV_, S_, (long)S_ * S_, (long)DV_ * S_, (long)S_ * DV_, 1.f);
  }
}

// Round 7
// 344.068 us; speedup vs baseline: 1.3851x; 1.0304x over previous
//
#include <hip/hip_runtime.h>
#include <stdint.h>

// Problem constants (B,S,D fixed by the reference)
#define B_  4
#define S_  2048
#define D_  1024
#define DK_ 1024
#define DV_ 1024

typedef __attribute__((ext_vector_type(8)))  short short8;    // 8 bf16 = 4 VGPRs (MFMA A/B frag)
typedef __attribute__((ext_vector_type(16))) float floatx16;  // 32x32 MFMA C/D frag

// async global->LDS DMA, 16B per lane, wave-uniform LDS base (lane scatters +lane*16B)
#define ASYNC16(gsrc, ldst)                                                        \
  __builtin_amdgcn_global_load_lds(                                                \
      (const __attribute__((address_space(1))) unsigned int*)(gsrc),               \
      (__attribute__((address_space(3))) unsigned int*)(ldst), 16, 0, 0)

// round-to-nearest-even fp32 -> bf16
__device__ __forceinline__ unsigned short f2bf(float f) {
  union { float f; uint32_t u; } v; v.f = f;
  uint32_t r = v.u + 0x7fffu + ((v.u >> 16) & 1u);
  return (unsigned short)(r >> 16);
}

// ---------------- prep: fp32->bf16 for q/k/v  +  W^T (bf16), one dispatch ----------------
// blocks [0,12288): conversion, 2048 elems/block (tensor = bid/4096)
// blocks [12288,15360): 32x32 transpose tiles of Wq/Wk/Wv
__global__ __launch_bounds__(256)
void prep(const float* __restrict__ q, const float* __restrict__ k, const float* __restrict__ v,
          const float* __restrict__ W0, const float* __restrict__ W1, const float* __restrict__ W2,
          unsigned short* __restrict__ qkv, unsigned short* __restrict__ WT) {
  const int bid = blockIdx.x, tid = threadIdx.x;
  if (bid < 12288) {
    const int t  = bid >> 12;         // tensor 0..2
    const int cb = bid & 4095;        // chunk within tensor
    const float* in = (t == 0) ? q : (t == 1) ? k : v;
    unsigned short* o = qkv + (long)t * ((long)B_ * S_ * D_);
    const int i0 = cb * 512 + tid;    // float4 index (512 per block)
    float4 v0 = ((const float4*)in)[i0];
    float4 v1 = ((const float4*)in)[i0 + 256];
    ushort4 u0, u1;
    u0.x = f2bf(v0.x); u0.y = f2bf(v0.y); u0.z = f2bf(v0.z); u0.w = f2bf(v0.w);
    u1.x = f2bf(v1.x); u1.y = f2bf(v1.y); u1.z = f2bf(v1.z); u1.w = f2bf(v1.w);
    ((ushort4*)o)[i0] = u0;
    ((ushort4*)o)[i0 + 256] = u1;
  } else {
    const int b2 = bid - 12288;
    const int w  = b2 >> 10;          // weight 0..2
    const int tl = b2 & 1023;         // 32x32 tile id
    const float* in = (w == 0) ? W0 : (w == 1) ? W1 : W2;
    unsigned short* o = WT + (long)w * D_ * DK_;
    __shared__ float tile[32][33];
    const int bx = (tl & 31) * 32, by = (tl >> 5) * 32;
    const int tx = tid & 31, ty = tid >> 5;
    for (int r = ty; r < 32; r += 8)
      tile[r][tx] = in[(long)(by + r) * DK_ + bx + tx];
    __syncthreads();
    for (int r = ty; r < 32; r += 8)
      o[(long)(bx + r) * D_ + by + tx] = f2bf(tile[tx][r]);
  }
}

__device__ __forceinline__ void storeC(float* p, float v)          { *p = v; }
__device__ __forceinline__ void storeC(unsigned short* p, float v) { *p = f2bf(v); }

// ---------------- bf16 BT GEMM, 32x32x16 MFMA, BK=64, XOR(row>>1) swizzle ----------------
// C[M,N] = scale * (A[M,K] . B[N,K]^T) + bias.  128x128 block tile, 4 waves (2x2 of 64x64).
// Swizzle (round-6 verified: conflicts 18.9M->6.3M, DMA coalescing kept):
//   kc_lds = kc ^ ((row>>1)&3), applied on global DMA source within each 64B line.
// A/B frag (32x32x16): m(or n)=lane&31, k-chunk=(s&1)*2+(lane>>5).
// C/D (m74/m101 verified): col=lane&31, row=(reg&3)+8*(reg>>2)+4*(lane>>5).
// NOUT=3: fused QKV (blockIdx.x selects A/C/bias; B spans 3072 rows). sel==2 stores V
//   TRANSPOSED into Vt[B][DV][S] (16 rows per lane are contiguous in S -> ushort4 stores).
// MODE: 0 = plain (+bias);  1 = store exp(val) + atomicAdd per-row sums (unnormalized
//   softmax; scores bounded so no max-subtraction needed);  2 = multiply by 1/rowsum.
template <typename OutT, int NOUT, int MODE>
__global__ __launch_bounds__(256)
void gemm_bt32(const unsigned short* __restrict__ A0, const unsigned short* __restrict__ A1,
               const unsigned short* __restrict__ A2, const unsigned short* __restrict__ Bm,
               OutT* __restrict__ C0, OutT* __restrict__ C1, OutT* __restrict__ C2,
               const float* __restrict__ b0, const float* __restrict__ b1,
               const float* __restrict__ b2, float* __restrict__ rowsum,
               int N, int K, long sA, long sB, long sC, float scale) {
  __shared__ __align__(16) unsigned short As[2][128 * 32];
  __shared__ __align__(16) unsigned short Bs[2][128 * 32];
  __shared__ float invs[128];
  const int tid  = threadIdx.x;
  const int lane = tid & 63, wave = tid >> 6;
  const int wm = (wave >> 1) * 64, wn = (wave & 1) * 64;
  const int lm = lane & 31;
  const int hi = lane >> 5;
  const long zb = blockIdx.z;
  const int m0  = blockIdx.y * 128;
  const int n0g = blockIdx.x * 128;

  const unsigned short* A = A0;
  OutT* C = C0;
  const float* bias = b0;
  int n0 = n0g, sel = 0;
  if (NOUT == 3) {
    sel = n0g >> 10;
    n0 = n0g & 1023;
    if (sel == 1)      { A = A1; C = C1; bias = b1; }
    else if (sel == 2) { A = A2; C = C2; bias = b2; }
  }
  A += zb * sA;
  const unsigned short* Bp = Bm + zb * sB;
  C += zb * sC;

  // ---- staging: per wave 4 A-chunks + 4 B-chunks per K=64 iter (coalesced, swizzled src) ----
  const int rr = lane >> 2;
  const int cc = (((lane & 3) ^ ((lane >> 3) & 3)) * 8);
  const unsigned short* agA = A  + (long)(m0  + 16 * wave + rr) * K + cc;
  const unsigned short* agB = Bp + (long)(n0g + 16 * wave + rr) * K + cc;
  const unsigned short* ag0 = agA;
  const unsigned short* ag1 = agA + 32;
  const unsigned short* ag2 = agA + 64 * (long)K;
  const unsigned short* ag3 = agA + 64 * (long)K + 32;
  const unsigned short* bg0 = agB;
  const unsigned short* bg1 = agB + 32;
  const unsigned short* bg2 = agB + 64 * (long)K;
  const unsigned short* bg3 = agB + 64 * (long)K + 32;
  unsigned short* al0 = &As[0][wave * 512];
  unsigned short* al1 = &As[1][wave * 512];
  unsigned short* al2 = &As[0][(wave + 4) * 512];
  unsigned short* al3 = &As[1][(wave + 4) * 512];
  unsigned short* bl0 = &Bs[0][wave * 512];
  unsigned short* bl1 = &Bs[1][wave * 512];
  unsigned short* bl2 = &Bs[0][(wave + 4) * 512];
  unsigned short* bl3 = &Bs[1][(wave + 4) * 512];

  floatx16 acc[2][2] = {};
  const int sw = (lm >> 1) & 3;

  for (int kt = 0; kt < K; kt += 64) {
    __syncthreads();
    ASYNC16(ag0, al0); ASYNC16(ag1, al1); ASYNC16(ag2, al2); ASYNC16(ag3, al3);
    ASYNC16(bg0, bl0); ASYNC16(bg1, bl1); ASYNC16(bg2, bl2); ASYNC16(bg3, bl3);
    __syncthreads();

#pragma unroll
    for (int s = 0; s < 4; s++) {
      const int h   = s >> 1;
      const int off = (((s & 1) * 2 + hi) ^ sw) * 8;
      short8 af[2], bf[2];
#pragma unroll
      for (int i = 0; i < 2; i++)
        af[i] = *(const short8*)&As[h][(wm + i * 32 + lm) * 32 + off];
#pragma unroll
      for (int j = 0; j < 2; j++)
        bf[j] = *(const short8*)&Bs[h][(wn + j * 32 + lm) * 32 + off];
#pragma unroll
      for (int i = 0; i < 2; i++)
#pragma unroll
        for (int j = 0; j < 2; j++)
          acc[i][j] = __builtin_amdgcn_mfma_f32_32x32x16_bf16(af[i], bf[j], acc[i][j], 0, 0, 0);
    }
    ag0 += 64; ag1 += 64; ag2 += 64; ag3 += 64;
    bg0 += 64; bg1 += 64; bg2 += 64; bg3 += 64;
  }

  // ---- MODE 2: stage 1/rowsum for this block's 128 rows ----
  if (MODE == 2) {
    __syncthreads();   // all waves done with LDS reads; safe to reuse schedule slot
    if (tid < 128) invs[tid] = 1.0f / rowsum[zb * S_ + m0 + tid];
    __syncthreads();
  }

  // ---- epilogue: C/D col=lane&31, row=(r&3)+8*(r>>2)+4*hi ----
  if (NOUT == 3 && sel == 2) {
    // V output, stored transposed into Vt[B][DV][S]
    unsigned short* Vt = (unsigned short*)C;
    const int b = m0 >> 11;              // batch (2048 rows per batch)
    const int sbase = (m0 & 2047);
#pragma unroll
    for (int i = 0; i < 2; i++) {
      const int srowb = sbase + wm + i * 32 + (hi << 2);
#pragma unroll
      for (int j = 0; j < 2; j++) {
        const int col = n0 + wn + j * 32 + lm;
        const float bv = bias[col];
        unsigned short* vp = Vt + ((long)b * DV_ + col) * S_ + srowb;
#pragma unroll
        for (int g = 0; g < 4; g++) {
          ushort4 u;
          u.x = f2bf(acc[i][j][4 * g + 0] + bv);
          u.y = f2bf(acc[i][j][4 * g + 1] + bv);
          u.z = f2bf(acc[i][j][4 * g + 2] + bv);
          u.w = f2bf(acc[i][j][4 * g + 3] + bv);
          *(ushort4*)(vp + 8 * g) = u;
        }
      }
    }
  } else if (MODE == 1) {
    // scores: store U = exp(score), accumulate row sums (shfl-reduce + 1 atomic per 32 lanes)
#pragma unroll
    for (int i = 0; i < 2; i++) {
#pragma unroll
      for (int r = 0; r < 16; r++) {
        const int row = m0 + wm + i * 32 + (r & 3) + ((r >> 2) << 3) + (hi << 2);
        float sum2 = 0.f;
#pragma unroll
        for (int j = 0; j < 2; j++) {
          const int col = n0 + wn + j * 32 + lm;
          float e = __expf(acc[i][j][r] * scale);
          storeC(C + (long)row * N + col, e);
          sum2 += e;
        }
#pragma unroll
        for (int msk = 1; msk < 32; msk <<= 1) sum2 += __shfl_xor(sum2, msk, 64);
        if ((lane & 31) == 0) atomicAdd(&rowsum[zb * S_ + row], sum2);
      }
    }
  } else {
#pragma unroll
    for (int i = 0; i < 2; i++) {
#pragma unroll
      for (int j = 0; j < 2; j++) {
        const int col = n0 + wn + j * 32 + lm;
        const float bv = bias ? bias[col] : 0.f;
#pragma unroll
        for (int r = 0; r < 16; r++) {
          const int rl = wm + i * 32 + (r & 3) + ((r >> 2) << 3) + (hi << 2);
          float val = acc[i][j][r] * scale + bv;
          if (MODE == 2) val *= invs[rl];
          storeC(C + (long)(m0 + rl) * N + col, val);
        }
      }
    }
  }
}

extern "C" void kernel_launch(void* const* d_in, const int* in_sizes, int n_in,
                              void* d_out, int out_size, void* d_ws, size_t ws_size,
                              hipStream_t stream) {
  const float* q_in = (const float*)d_in[0];
  const float* k_in = (const float*)d_in[1];
  const float* v_in = (const float*)d_in[2];
  const float* Wq   = (const float*)d_in[3];
  const float* bq   = (const float*)d_in[4];
  const float* Wk   = (const float*)d_in[5];
  const float* bk   = (const float*)d_in[6];
  const float* Wv   = (const float*)d_in[7];
  const float* bv   = (const float*)d_in[8];
  float* out = (float*)d_out;

  // ---- workspace layout; U (bf16 scores) overlays dead qb/kb/vb after QKV ----
  char* ws = (char*)d_ws;
  const long nX = (long)B_ * S_ * D_;   // 8388608 elems
  const long nW = (long)D_ * DK_;       // 1048576
  unsigned short* qb  = (unsigned short*)(ws);
  unsigned short* kb  = qb + nX;
  unsigned short* vb  = kb + nX;
  unsigned short* WqT = vb + nX;        // 3 contiguous = B[3072,1024]
  unsigned short* Qb  = WqT + 3 * nW;
  unsigned short* Kb  = Qb + nX;
  unsigned short* Vt  = Kb + nX;        // [B, DV, S] written directly by QKV epilogue
  float*          rowsum = (float*)(Vt + nX);     // B*S fp32 = 32KB
  unsigned short* U   = (unsigned short*)ws;      // bf16 [B,S,S] overlay (qb/kb/vb dead)

  dim3 blk(256);

  // 0) zero rowsum (ws is re-poisoned 0xAA before every launch)
  hipMemsetAsync(rowsum, 0, (size_t)B_ * S_ * sizeof(float), stream);

  // 1) prep: q/k/v -> bf16 and W -> W^T bf16, one dispatch
  {
    dim3 g(12288 + 3072);
    prep<<<g, blk, 0, stream>>>(q_in, k_in, v_in, Wq, Wk, Wv, qb, WqT);
  }
  // 2) fused QKV projection; V stored transposed into Vt
  {
    dim3 g(3 * DK_ / 128, (B_ * S_) / 128, 1);
    gemm_bt32<unsigned short, 3, 0><<<g, blk, 0, stream>>>(
        qb, kb, vb, WqT, Qb, Kb, Vt, bq, bk, bv, nullptr, DK_, D_, 0, 0, 0, 1.f);
  }
  // 3) U = exp(Q K^T / 32) -> bf16, + per-row sums (atomics)
  {
    dim3 g(S_ / 128, S_ / 128, B_);
    gemm_bt32<unsigned short, 1, 1><<<g, blk, 0, stream>>>(
        Qb, nullptr, nullptr, Kb, U, nullptr, nullptr, nullptr, nullptr, nullptr, rowsum,
        S_, DK_, (long)S_ * DK_, (long)S_ * DK_, (long)S_ * S_, 0.03125f);
  }
  // 4) out = (U @ V) / rowsum = U[2048,2048] x Vt[1024,2048]^T, normalized in epilogue
  {
    dim3 g(DV_ / 128, S_ / 128, B_);
    gemm_bt32<float, 1, 2><<<g, blk, 0, stream>>>(
        U, nullptr, nullptr, Vt, out, nullptr, nullptr, nullptr, nullptr, nullptr, rowsum,
        DV_, S_, (long)S_ * S_, (long)DV_ * S_, (long)S_ * DV_, 1.f);
  }
}